// Round 18
// baseline (189.449 us; speedup 1.0000x reference)
//
#include <hip/hip_runtime.h>

#define NWIN 1000
#define HID  30
#define ANC  7
#define BATCH 64
#define KS   75
#define PADH 37
#define OBASE_ELEMS (BATCH*ANC*NWIN*2)   // 896000

#define WPITCH 40          // floats per W row in LDS (160B, 16B-aligned)
#define WROWS  504
#define RING_D 16          // x ring depth (steps); 1 step = 8 positions
#define NSTEP  63          // 63*8 = 504 positions (500 real + 4 zero-padded)

// hs4 overlay into wlds after the K loop: 4 partial buffers, pitch 65
#define HS4(k,b,col) ((k)*4160 + (b)*65 + (col))

typedef float v2f __attribute__((ext_vector_type(2)));
typedef float v4f __attribute__((ext_vector_type(4)));

__device__ __forceinline__ void gload_lds4(const float* g, float* l) {
    __builtin_amdgcn_global_load_lds(
        (const __attribute__((address_space(1))) void*)g,
        (__attribute__((address_space(3))) void*)l, 4, 0, 0);
}
__device__ __forceinline__ void gload_lds16(const float* g, float* l) {
    __builtin_amdgcn_global_load_lds(
        (const __attribute__((address_space(1))) void*)g,
        (__attribute__((address_space(3))) void*)l, 16, 0, 0);
}
__device__ __forceinline__ unsigned lds_off(const void* p) {
    return (unsigned)(unsigned long long)
        (const __attribute__((address_space(3))) void*)p;
}

// ---------------------------------------------------------------------------
// Kernel 1 (v16): whole-W-in-LDS + per-wave x RING BUFFER in LDS with counted
// vmcnt -- NO barriers in the K loop. Diagnosis R16: every structure pays
// ~300-390 cy/position = exposed x-load latency; TLP is capped at 2-4
// waves/SIMD by the VGPR law (waves/SIMD ~ floor(256/VGPR)), so latency must
// be hidden by DEPTH, not waves. The ring gives 16 steps (~5K cy) lookahead
// with zero staging registers: per step each wave issues one gload_lds4
// (64 lanes = 4 batches x 8 pos x 2 ch, per-lane source, linear dest into
// its private slot), waits vmcnt(15) (its own queue), reads the slot via
// inline-asm ds_read_b128 x2 (invisible to compiler alias analysis -> no
// forced vmcnt(0) drains), lgkmcnt(0)+sched_barrier before slot reuse.
// wave = 4 batches; lane = (pg 0..7 pos-in-step, jq 0..7 j-quad):
// acc[4b][4j][2c] = 32 VGPR. W: [504][40] resident (80.6KB); ring 64KB.
// ---------------------------------------------------------------------------
__global__ __launch_bounds__(1024, 4) void k1(
        const float* __restrict__ x,
        const float* __restrict__ W1, const float* __restrict__ b1,
        const float* __restrict__ W2, const float* __restrict__ b2,
        float* __restrict__ out_base)
{
    __shared__ float wlds[WROWS * WPITCH];        // 80,640 B
    __shared__ float xring[RING_D * 16 * 64];     // 65,536 B  (tot 146,176)

    const int n    = blockIdx.x;
    const int t    = threadIdx.x;
    const int wid  = __builtin_amdgcn_readfirstlane(t >> 6);   // 0..15
    const int lane = t & 63;
    const int pg   = lane & 7;         // consumer: position-in-step
    const int jq   = lane >> 3;        // consumer: j-quad 0..7
    const int b0   = wid * 4;          // wave's batch base
    const int j0   = jq * 4;

    // producer mapping: lane <-> element (p, bb, c), element index = lane
    const int pp  = lane >> 3;         // position-in-step 0..7
    const int pbb = (lane >> 1) & 3;   // batch-in-quad
    const int pc  = lane & 1;          // channel
    const float* __restrict__ gxl = x + (size_t)(b0 + pbb) * 1000000u
                                      + (size_t)n * 1000u + pc;

    float acc[4][4][2];
#pragma unroll
    for (int i = 0; i < 4; ++i)
#pragma unroll
        for (int j = 0; j < 4; ++j) { acc[i][j][0] = 0.f; acc[i][j][1] = 0.f; }

    // ---- prologue: issue x ring steps 0..15 (per-wave private slots) -----
    float* const slot_base = &xring[wid * 64];    // + slot*1024 floats... (16 waves *64)
#pragma unroll
    for (int s = 0; s < RING_D; ++s) {
        const int pos = s * 8 + pp;               // <= 127, valid
        gload_lds4(gxl + pos * 2, &xring[(s * 16 + wid) * 64]);
    }

    // ---- stage whole-window W into LDS (granule g -> row g/10, col (g%10)*4)
    {
        const float* __restrict__ gw = W1 + (size_t)n * 15000u;
#pragma unroll
        for (int r = 0; r < 5; ++r) {
            const int g = t + r * 1024;
            if (g < 5040) {
                const int row  = g / 10;
                const int col  = (g % 10) * 4;
                const int srow = row < 500 ? row : 499;
                const int scol = col < 28 ? col : 28;
                gload_lds16(gw + srow * 30 + scol,
                            &wlds[((t & 0x3C0) + r * 1024) * 4]);
            }
        }
    }
    __syncthreads();                         // drains ALL vmcnt -> count = 0
    if (t < 160) wlds[20000 + t] = 0.f;      // zero W rows 500..503
    __syncthreads();

    // ---- K loop: 63 steps, NO barriers, counted vmcnt ---------------------
    const unsigned xbase = lds_off(&xring[0]) + (unsigned)(wid * 256 + pg * 32);
    for (int s = 0; s < NSTEP; ++s) {
        // (1) oldest of the 16 in-flight ring loads (step s) has landed
        asm volatile("s_waitcnt vmcnt(15)" ::: "memory");

        // (2) read slot s: 8 floats = 4 batches x 2 ch for position pg
        const unsigned xaddr = xbase + ((unsigned)(s & 15) << 12);
        v4f xq0, xq1;
        asm volatile("ds_read_b128 %0, %1 offset:0"  : "=v"(xq0) : "v"(xaddr));
        asm volatile("ds_read_b128 %0, %1 offset:16" : "=v"(xq1) : "v"(xaddr));

        // (3) W row for this lane's position (C++; separate array, no alias)
        const float4 wf = *reinterpret_cast<const float4*>(
            &wlds[(s * 8 + pg) * WPITCH + j0]);

        // (4) all LDS reads complete before slot reuse / FMA consumption
        asm volatile("s_waitcnt lgkmcnt(0)" ::: "memory");
        __builtin_amdgcn_sched_barrier(0);

        // (5) refill: issue step s+16 into the slot just consumed
        {
            int pos = (s + RING_D) * 8 + pp;
            pos = pos > 499 ? 499 : pos;     // tail junk x zeroed-W rows
            gload_lds4(gxl + pos * 2, &xring[((s & 15) * 16 + wid) * 64]);
        }

        // (6) 32 FMA + 8 transforms
        const float wv0 = wf.x, wv1 = wf.y, wv2 = wf.z, wv3 = wf.w;
        const v2f xv[4] = { {xq0.x, xq0.y}, {xq0.z, xq0.w},
                            {xq1.x, xq1.y}, {xq1.z, xq1.w} };
#pragma unroll
        for (int ii = 0; ii < 4; ++ii) {
            const float a0 = fmaf(2.f, xv[ii].x, -1.f);
            const float a1 = fmaf(2.f, xv[ii].y, -1.f);
            acc[ii][0][0] = fmaf(a0, wv0, acc[ii][0][0]);
            acc[ii][1][0] = fmaf(a0, wv1, acc[ii][1][0]);
            acc[ii][2][0] = fmaf(a0, wv2, acc[ii][2][0]);
            acc[ii][3][0] = fmaf(a0, wv3, acc[ii][3][0]);
            acc[ii][0][1] = fmaf(a1, wv0, acc[ii][0][1]);
            acc[ii][1][1] = fmaf(a1, wv1, acc[ii][1][1]);
            acc[ii][2][1] = fmaf(a1, wv2, acc[ii][2][1]);
            acc[ii][3][1] = fmaf(a1, wv3, acc[ii][3][1]);
        }
    }
    (void)slot_base;

    // ---- reduce pg-pairs in-register, then 4 partials via LDS overlay -----
#pragma unroll
    for (int ii = 0; ii < 4; ++ii)
#pragma unroll
        for (int jj = 0; jj < 4; ++jj) {
            acc[ii][jj][0] += __shfl_xor(acc[ii][jj][0], 1);
            acc[ii][jj][1] += __shfl_xor(acc[ii][jj][1], 1);
        }
    __syncthreads();                   // all waves done reading W region
    if ((pg & 1) == 0) {
        const int k = pg >> 1;         // 0..3
#pragma unroll
        for (int ii = 0; ii < 4; ++ii)
#pragma unroll
            for (int jj = 0; jj < 4; ++jj) {
                const int j = j0 + jj;
                if (j < 30) {
                    wlds[HS4(k, b0 + ii, j)]      = acc[ii][jj][0];
                    wlds[HS4(k, b0 + ii, 30 + j)] = acc[ii][jj][1];
                }
            }
    }
    __syncthreads();

    // ---- bias + relu + two-pass batch stats + normalize -------------------
    {
        const int bb = t & 63;
        const int c2 = (t >> 6) & 1;
        const int jg = t >> 7;             // 0..7
#pragma unroll
        for (int k = 0; k < 4; ++k) {
            const int j = jg * 4 + k;
            if (j < 30) {
                const int col = c2 * 30 + j;
                float v = wlds[HS4(0, bb, col)] + wlds[HS4(1, bb, col)]
                        + wlds[HS4(2, bb, col)] + wlds[HS4(3, bb, col)]
                        + b1[n * HID + j];
                v = fmaxf(v, 0.f);
                float s = v;
#pragma unroll
                for (int off = 32; off > 0; off >>= 1) s += __shfl_xor(s, off);
                const float mean = s * (1.f / 64.f);
                const float d = v - mean;
                float ss = d * d;
#pragma unroll
                for (int off = 32; off > 0; off >>= 1) ss += __shfl_xor(ss, off);
                const float var = ss * (1.f / 64.f);
                const float rn  = rsqrtf(var + 1e-5f);
                wlds[HS4(0, bb, col)] = d * rn;
            }
        }
    }
    __syncthreads();

    // ---- GEMM2 + write out_base[b][a][n][c] -------------------------------
    if (t < BATCH * ANC) {
        const int bb = t / 7, a = t - bb * 7;
        const float* __restrict__ w2p = W2 + (size_t)n * (HID * ANC);
        float o0 = b2[n * ANC + a], o1 = o0;
#pragma unroll
        for (int h = 0; h < HID; ++h) {
            const float wv = w2p[h * ANC + a];
            o0 = fmaf(wlds[HS4(0, bb, h)],      wv, o0);
            o1 = fmaf(wlds[HS4(0, bb, 30 + h)], wv, o1);
        }
        reinterpret_cast<float2*>(out_base)[((size_t)bb * ANC + a) * NWIN + n]
            = make_float2(o0, o1);
    }
}

// ---------------------------------------------------------------------------
// Kernel 2: softmax over ANC + reflect-pad + conv (2 needed output columns)
// via sum/diff factorization. Unchanged (~7us).
// ---------------------------------------------------------------------------
__global__ __launch_bounds__(256, 2) void k2(
        const float* __restrict__ out_base,
        const float* __restrict__ conv_w, const float* __restrict__ conv_b,
        float* __restrict__ out_smooth)
{
    __shared__ float2 sdl[199 * ANC];
    __shared__ float2 wael[ANC * ANC * KS];

    const int bidx = blockIdx.x;
    const int b  = bidx >> 3;
    const int ht = bidx & 7;
    const int h0 = ht * 125;
    const int t  = threadIdx.x;

    const float2* __restrict__ cw2 = reinterpret_cast<const float2*>(conv_w);
    for (int idx = t; idx < ANC * ANC * KS; idx += 256) {
        const float2 w = cw2[idx];
        wael[idx] = make_float2(w.x + w.y, w.x - w.y);
    }

    if (t < 199) {
        const int hglob = h0 - PADH + t;
        const int hm = hglob < 0 ? -hglob
                     : (hglob >= NWIN ? 2 * NWIN - 2 - hglob : hglob);
        float p[2][ANC];
#pragma unroll
        for (int c = 0; c < 2; ++c) {
            float v[ANC];
            float m = -1e30f;
#pragma unroll
            for (int a = 0; a < ANC; ++a) {
                v[a] = out_base[(((size_t)b * ANC + a) * NWIN + hm) * 2 + c];
                m = fmaxf(m, v[a]);
            }
            float s = 0.f;
#pragma unroll
            for (int a = 0; a < ANC; ++a) { v[a] = __expf(v[a] - m); s += v[a]; }
            const float inv = 1.f / s;
#pragma unroll
            for (int a = 0; a < ANC; ++a) p[c][a] = v[a] * inv;
        }
#pragma unroll
        for (int a = 0; a < ANC; ++a)
            sdl[t * ANC + a] = make_float2(p[0][a] + p[1][a], p[0][a] - p[1][a]);
    }
    __syncthreads();

    for (int idx = t; idx < ANC * 125; idx += 256) {
        const int o  = idx / 125;
        const int hl = idx % 125;
        float sa = 0.f, de = 0.f;
        const float2* __restrict__ wrow = &wael[o * ANC * KS];
#pragma unroll 1
        for (int i = 0; i < ANC; ++i) {
            const float2* __restrict__ sdp = &sdl[hl * ANC + i];
            const float2* __restrict__ wp  = &wrow[i * KS];
#pragma unroll 5
            for (int kh = 0; kh < KS; ++kh) {
                const float2 sd = sdp[kh * ANC];
                const float2 we = wp[kh];
                sa = fmaf(sd.x, we.x, sa);
                de = fmaf(sd.y, we.y, de);
            }
        }
        const float cb = conv_b[o];
        const float o0 = 0.5f * (sa - de) + cb;
        const float o1 = 0.5f * (sa + de) + cb;
        const size_t base = (((size_t)b * ANC + o) * NWIN + (h0 + hl)) * 2;
        out_smooth[base + 0] = o0;
        out_smooth[base + 1] = o1;
    }
}

extern "C" void kernel_launch(void* const* d_in, const int* in_sizes, int n_in,
                              void* d_out, int out_size, void* d_ws, size_t ws_size,
                              hipStream_t stream)
{
    const float* x      = (const float*)d_in[0];
    const float* W1     = (const float*)d_in[1];
    const float* b1     = (const float*)d_in[2];
    const float* W2     = (const float*)d_in[3];
    const float* b2     = (const float*)d_in[4];
    const float* conv_w = (const float*)d_in[5];
    const float* conv_b = (const float*)d_in[6];
    float* out = (float*)d_out;

    k1<<<dim3(NWIN), dim3(1024), 0, stream>>>(x, W1, b1, W2, b2, out);
    k2<<<dim3(BATCH * 8), dim3(256), 0, stream>>>(out, conv_w, conv_b,
                                                  out + OBASE_ELEMS);
}